// Round 2
// baseline (8057.761 us; speedup 1.0000x reference)
//
#include <hip/hip_runtime.h>
#include <hip/hip_bf16.h>
#include <math.h>

#define DEV __device__ __forceinline__

// ---------------------------------------------------------------- transpose
__global__ void k_tpose(const float* __restrict__ in, float* __restrict__ out, int N, int K) {
    int total = N * K;
    for (int idx = blockIdx.x * blockDim.x + threadIdx.x; idx < total; idx += gridDim.x * blockDim.x) {
        int n = idx / K, k = idx - n * K;
        out[k * N + n] = in[idx];
    }
}

// ---------------------------------------------------------------- conv1: [CB,20,8,8] -> a1 [CB,256,64], relu
__global__ __launch_bounds__(256) void k_conv1(const float* __restrict__ in, const float* __restrict__ w,
                                               const float* __restrict__ bias, float* __restrict__ out) {
    __shared__ __align__(16) float img[20 * 100];  // padded 10x10 per channel
    const int b = blockIdx.x;
    const int t = threadIdx.x;
    for (int idx = t; idx < 2000; idx += 256) {
        int c = idx / 100, pp = idx - c * 100;
        int y = pp / 10, x = pp - y * 10;
        float v = 0.f;
        if (y >= 1 && y <= 8 && x >= 1 && x <= 8)
            v = in[((size_t)b * 20 + c) * 64 + (y - 1) * 8 + (x - 1)];
        img[idx] = v;
    }
    __syncthreads();
    const int oc = t;
    float acc[64];
    const float bz = bias[oc];
#pragma unroll
    for (int p = 0; p < 64; ++p) acc[p] = bz;
    const float* wrow = w + oc * 180;
    for (int c = 0; c < 20; ++c) {
#pragma unroll
        for (int k = 0; k < 9; ++k) {
            const int ky = k / 3, kx = k - ky * 3;
            const float wv = wrow[c * 9 + k];
            const int base = c * 100 + ky * 10 + kx;
#pragma unroll
            for (int p = 0; p < 64; ++p)
                acc[p] = fmaf(wv, img[base + p + ((p >> 3) << 1)], acc[p]);
        }
    }
    float* orow = out + ((size_t)b * 256 + oc) * 64;
#pragma unroll
    for (int p = 0; p < 64; ++p) orow[p] = fmaxf(acc[p], 0.f);
}

// ---------------------------------------------------------------- conv2: a1 [CB,256,64] -> x [CB,64,256], relu
// w2t: [256 ic][9][256 oc] (pre-transposed)
__global__ __launch_bounds__(256) void k_conv2(const float* __restrict__ a1, const float* __restrict__ w2t,
                                               const float* __restrict__ bias, float* __restrict__ xout) {
    __shared__ __align__(16) float img[128 * 100];
    const int b = blockIdx.x;
    const int t = threadIdx.x;
    const int oc0 = (t & 63) * 4;
    const int pg = t >> 6;  // 0..3, 16 positions each
    const int pos0 = pg * 16;
    float acc[4][16];
#pragma unroll
    for (int i = 0; i < 4; ++i) {
        const float bz = bias[oc0 + i];
#pragma unroll
        for (int j = 0; j < 16; ++j) acc[i][j] = bz;
    }
    for (int half = 0; half < 2; ++half) {
        __syncthreads();
        for (int idx = t; idx < 12800; idx += 256) {
            int c = idx / 100, pp = idx - c * 100;
            int y = pp / 10, x = pp - y * 10;
            float v = 0.f;
            if (y >= 1 && y <= 8 && x >= 1 && x <= 8)
                v = a1[((size_t)b * 256 + half * 128 + c) * 64 + (y - 1) * 8 + (x - 1)];
            img[idx] = v;
        }
        __syncthreads();
        for (int ic = 0; ic < 128; ++ic) {
            const float* wbase = w2t + (size_t)((half * 128 + ic) * 9) * 256 + oc0;
#pragma unroll
            for (int k = 0; k < 9; ++k) {
                const int ky = k / 3, kx = k - ky * 3;
                const float4 w4 = *(const float4*)(wbase + k * 256);
                const int rb = ic * 100 + ky * 10 + kx + pg * 20;
#pragma unroll
                for (int j = 0; j < 16; ++j) {
                    const float v = img[rb + j + ((j >> 3) << 1)];
                    acc[0][j] = fmaf(v, w4.x, acc[0][j]);
                    acc[1][j] = fmaf(v, w4.y, acc[1][j]);
                    acc[2][j] = fmaf(v, w4.z, acc[2][j]);
                    acc[3][j] = fmaf(v, w4.w, acc[3][j]);
                }
            }
        }
    }
#pragma unroll
    for (int j = 0; j < 16; ++j) {
        float4 o4 = make_float4(fmaxf(acc[0][j], 0.f), fmaxf(acc[1][j], 0.f),
                                fmaxf(acc[2][j], 0.f), fmaxf(acc[3][j], 0.f));
        *(float4*)(xout + ((size_t)b * 64 + pos0 + j) * 256 + oc0) = o4;
    }
}

// ---------------------------------------------------------------- fused attention per (b, head)
// wqkvT: [256 k][768 rows] (pre-transposed in_proj_w)
__global__ __launch_bounds__(512) void k_attn(const float* __restrict__ x, const float* __restrict__ wqkvT,
                                              const float* __restrict__ bqkv, float* __restrict__ o) {
    __shared__ __align__(16) float qs[64 * 65];  // q, then reused for P
    __shared__ __align__(16) float ks[64 * 68];  // k, then reused for output staging
    __shared__ __align__(16) float vs[64 * 68];
    __shared__ float pmax[8 * 64];
    __shared__ float psum[8 * 64];
    const int b = blockIdx.x, h = blockIdx.y;
    const int t = threadIdx.x;
    const int d = t & 63;
    const int pg = t >> 6;  // wave id: 8 positions each
    float aq[8], ak[8], av[8];
#pragma unroll
    for (int j = 0; j < 8; ++j) { aq[j] = 0.f; ak[j] = 0.f; av[j] = 0.f; }
    const float* xrow = x + ((size_t)b * 64 + pg * 8) * 256;
    const int colq = h * 64 + d;
    for (int kk = 0; kk < 256; kk += 4) {
        float wq[4], wk[4], wv[4];
#pragma unroll
        for (int i = 0; i < 4; ++i) {
            const float* wr = wqkvT + (size_t)(kk + i) * 768;
            wq[i] = wr[colq]; wk[i] = wr[256 + colq]; wv[i] = wr[512 + colq];
        }
#pragma unroll
        for (int j = 0; j < 8; ++j) {
            const float4 xv = *(const float4*)(xrow + j * 256 + kk);
            aq[j] = fmaf(xv.x, wq[0], aq[j]); aq[j] = fmaf(xv.y, wq[1], aq[j]);
            aq[j] = fmaf(xv.z, wq[2], aq[j]); aq[j] = fmaf(xv.w, wq[3], aq[j]);
            ak[j] = fmaf(xv.x, wk[0], ak[j]); ak[j] = fmaf(xv.y, wk[1], ak[j]);
            ak[j] = fmaf(xv.z, wk[2], ak[j]); ak[j] = fmaf(xv.w, wk[3], ak[j]);
            av[j] = fmaf(xv.x, wv[0], av[j]); av[j] = fmaf(xv.y, wv[1], av[j]);
            av[j] = fmaf(xv.z, wv[2], av[j]); av[j] = fmaf(xv.w, wv[3], av[j]);
        }
    }
    const float bq = bqkv[colq], bk = bqkv[256 + colq], bv = bqkv[512 + colq];
#pragma unroll
    for (int j = 0; j < 8; ++j) {
        const int p = pg * 8 + j;
        qs[p * 65 + d] = aq[j] + bq;
        ks[p * 68 + d] = ak[j] + bk;
        vs[p * 68 + d] = av[j] + bv;
    }
    __syncthreads();
    // scores: thread (r = t&63, cg = t>>6) computes s[r][cg*8 .. cg*8+7]
    const int r = t & 63;
    const int cg = t >> 6;
    float sc[8];
#pragma unroll
    for (int j = 0; j < 8; ++j) sc[j] = 0.f;
    for (int kk = 0; kk < 64; kk += 4) {
        float qv[4];
#pragma unroll
        for (int i = 0; i < 4; ++i) qv[i] = qs[r * 65 + kk + i];
#pragma unroll
        for (int j = 0; j < 8; ++j) {
            const float4 kv = *(const float4*)(ks + (cg * 8 + j) * 68 + kk);
            sc[j] = fmaf(qv[0], kv.x, sc[j]); sc[j] = fmaf(qv[1], kv.y, sc[j]);
            sc[j] = fmaf(qv[2], kv.z, sc[j]); sc[j] = fmaf(qv[3], kv.w, sc[j]);
        }
    }
    float pm = -1e30f;
#pragma unroll
    for (int j = 0; j < 8; ++j) { sc[j] *= 0.125f; pm = fmaxf(pm, sc[j]); }
    pmax[cg * 64 + r] = pm;
    __syncthreads();
    float m = pmax[r];
#pragma unroll
    for (int i = 1; i < 8; ++i) m = fmaxf(m, pmax[i * 64 + r]);
    float pe[8], ps = 0.f;
#pragma unroll
    for (int j = 0; j < 8; ++j) { pe[j] = __expf(sc[j] - m); ps += pe[j]; }
    psum[cg * 64 + r] = ps;
    __syncthreads();
    float den = psum[r];
#pragma unroll
    for (int i = 1; i < 8; ++i) den += psum[i * 64 + r];
    const float rden = 1.f / den;
#pragma unroll
    for (int j = 0; j < 8; ++j) qs[r * 65 + cg * 8 + j] = pe[j] * rden;  // P overwrites q
    __syncthreads();
    // PV: thread (r, dg = cg) computes o[r][dg*8 .. +7]
    float oa[8];
#pragma unroll
    for (int j = 0; j < 8; ++j) oa[j] = 0.f;
    for (int c = 0; c < 64; ++c) {
        const float pv = qs[r * 65 + c];
        const float4 v0 = *(const float4*)(vs + c * 68 + cg * 8);
        const float4 v1 = *(const float4*)(vs + c * 68 + cg * 8 + 4);
        oa[0] = fmaf(pv, v0.x, oa[0]); oa[1] = fmaf(pv, v0.y, oa[1]);
        oa[2] = fmaf(pv, v0.z, oa[2]); oa[3] = fmaf(pv, v0.w, oa[3]);
        oa[4] = fmaf(pv, v1.x, oa[4]); oa[5] = fmaf(pv, v1.y, oa[5]);
        oa[6] = fmaf(pv, v1.z, oa[6]); oa[7] = fmaf(pv, v1.w, oa[7]);
    }
#pragma unroll
    for (int j = 0; j < 8; ++j) ks[r * 68 + cg * 8 + j] = oa[j];  // stage into dead k
    __syncthreads();
    for (int idx = t; idx < 4096; idx += 512) {
        const int rr = idx >> 6, dd = idx & 63;
        o[((size_t)b * 64 + rr) * 256 + h * 64 + dd] = ks[rr * 68 + dd];
    }
}

// ---------------------------------------------------------------- generic fp32 GEMM: C = A[M,K] @ W[N,K]^T (+bias)(+relu)
// split-K via blockIdx.z: computes K-range [z*kChunk, (z+1)*kChunk), writes C + z*M*N
__global__ __launch_bounds__(256) void k_gemm(const float* __restrict__ A, const float* __restrict__ W,
                                              const float* __restrict__ bias, float* __restrict__ C,
                                              int M, int N, int K, int kChunk, int relu) {
    __shared__ __align__(16) float As[16 * 68];
    __shared__ __align__(16) float Bs[16 * 68];
    const int t = threadIdx.x;
    const int row0 = blockIdx.x * 64;
    const int col0 = blockIdx.y * 64;
    const int k0 = blockIdx.z * kChunk;
    const int k1 = k0 + kChunk;
    float* Cb = C + (size_t)blockIdx.z * M * N;
    const int tr = t >> 4, tc = t & 15;
    const int lr = t >> 2, lc = t & 3;
    float acc[4][4] = {};
    const float* Ap = A + (size_t)(row0 + lr) * K + lc * 4;
    const float* Wp = W + (size_t)(col0 + lr) * K + lc * 4;
    for (int kt = k0; kt < k1; kt += 16) {
        const float4 a4 = *(const float4*)(Ap + kt);
        const float4 w4 = *(const float4*)(Wp + kt);
        As[(lc * 4 + 0) * 68 + lr] = a4.x;
        As[(lc * 4 + 1) * 68 + lr] = a4.y;
        As[(lc * 4 + 2) * 68 + lr] = a4.z;
        As[(lc * 4 + 3) * 68 + lr] = a4.w;
        Bs[(lc * 4 + 0) * 68 + lr] = w4.x;
        Bs[(lc * 4 + 1) * 68 + lr] = w4.y;
        Bs[(lc * 4 + 2) * 68 + lr] = w4.z;
        Bs[(lc * 4 + 3) * 68 + lr] = w4.w;
        __syncthreads();
#pragma unroll
        for (int kk = 0; kk < 16; ++kk) {
            const float4 av = *(const float4*)(As + kk * 68 + tr * 4);
            const float4 bv = *(const float4*)(Bs + kk * 68 + tc * 4);
            acc[0][0] = fmaf(av.x, bv.x, acc[0][0]); acc[0][1] = fmaf(av.x, bv.y, acc[0][1]);
            acc[0][2] = fmaf(av.x, bv.z, acc[0][2]); acc[0][3] = fmaf(av.x, bv.w, acc[0][3]);
            acc[1][0] = fmaf(av.y, bv.x, acc[1][0]); acc[1][1] = fmaf(av.y, bv.y, acc[1][1]);
            acc[1][2] = fmaf(av.y, bv.z, acc[1][2]); acc[1][3] = fmaf(av.y, bv.w, acc[1][3]);
            acc[2][0] = fmaf(av.z, bv.x, acc[2][0]); acc[2][1] = fmaf(av.z, bv.y, acc[2][1]);
            acc[2][2] = fmaf(av.z, bv.z, acc[2][2]); acc[2][3] = fmaf(av.z, bv.w, acc[2][3]);
            acc[3][0] = fmaf(av.w, bv.x, acc[3][0]); acc[3][1] = fmaf(av.w, bv.y, acc[3][1]);
            acc[3][2] = fmaf(av.w, bv.z, acc[3][2]); acc[3][3] = fmaf(av.w, bv.w, acc[3][3]);
        }
        __syncthreads();
    }
    float4 bb = make_float4(0.f, 0.f, 0.f, 0.f);
    if (bias) bb = *(const float4*)(bias + col0 + tc * 4);
#pragma unroll
    for (int i = 0; i < 4; ++i) {
        float4 ov = make_float4(acc[i][0] + bb.x, acc[i][1] + bb.y, acc[i][2] + bb.z, acc[i][3] + bb.w);
        if (relu) {
            ov.x = fmaxf(ov.x, 0.f); ov.y = fmaxf(ov.y, 0.f);
            ov.z = fmaxf(ov.z, 0.f); ov.w = fmaxf(ov.w, 0.f);
        }
        *(float4*)(Cb + (size_t)(row0 + tr * 4 + i) * N + col0 + tc * 4) = ov;
    }
}

// ---------------------------------------------------------------- x = LN(x + add), rows of 256
__global__ __launch_bounds__(256) void k_ln_add(float* __restrict__ x, const float* __restrict__ add,
                                                const float* __restrict__ g, const float* __restrict__ bta) {
    const int t = threadIdx.x;
    const size_t r = (size_t)blockIdx.x * 4 + (t >> 6);
    const int lane = t & 63;
    float4 xv = *(const float4*)(x + r * 256 + lane * 4);
    const float4 av = *(const float4*)(add + r * 256 + lane * 4);
    const float4 v = make_float4(xv.x + av.x, xv.y + av.y, xv.z + av.z, xv.w + av.w);
    float s = v.x + v.y + v.z + v.w;
    float ss = fmaf(v.x, v.x, fmaf(v.y, v.y, fmaf(v.z, v.z, v.w * v.w)));
#pragma unroll
    for (int m = 32; m; m >>= 1) { s += __shfl_xor(s, m); ss += __shfl_xor(ss, m); }
    const float mean = s * (1.f / 256.f);
    const float var = ss * (1.f / 256.f) - mean * mean;
    const float rstd = rsqrtf(var + 1e-5f);
    const float4 g4 = *(const float4*)(g + lane * 4);
    const float4 b4 = *(const float4*)(bta + lane * 4);
    float4 ov;
    ov.x = (v.x - mean) * rstd * g4.x + b4.x;
    ov.y = (v.y - mean) * rstd * g4.y + b4.y;
    ov.z = (v.z - mean) * rstd * g4.z + b4.z;
    ov.w = (v.w - mean) * rstd * g4.w + b4.w;
    *(float4*)(x + r * 256 + lane * 4) = ov;
}

// ---------------------------------------------------------------- be1 split-K reduce + bias + relu (n = CB*256)
__global__ void k_be1_reduce(const float* __restrict__ parts, const float* __restrict__ bias,
                             float* __restrict__ out, int n) {
    const int idx = blockIdx.x * blockDim.x + threadIdx.x;
    if (idx < n) {
        float s = bias[idx & 255];
#pragma unroll
        for (int p = 0; p < 8; ++p) s += parts[(size_t)p * n + idx];
        out[idx] = fmaxf(s, 0.f);
    }
}

// ---------------------------------------------------------------- fused HRM recurrence (persistent, 8 rows/block)
DEV void dot_seg(float acc[4], const float* rowbase, const float* __restrict__ WT, int o) {
    for (int kk = 0; kk < 256; kk += 4) {
        const float w0 = WT[(kk + 0) * 256 + o];
        const float w1 = WT[(kk + 1) * 256 + o];
        const float w2 = WT[(kk + 2) * 256 + o];
        const float w3 = WT[(kk + 3) * 256 + o];
#pragma unroll
        for (int ri = 0; ri < 4; ++ri) {
            const float4 c4 = *(const float4*)(rowbase + ri * 256 + kk);
            acc[ri] = fmaf(c4.x, w0, acc[ri]);
            acc[ri] = fmaf(c4.y, w1, acc[ri]);
            acc[ri] = fmaf(c4.z, w2, acc[ri]);
            acc[ri] = fmaf(c4.w, w3, acc[ri]);
        }
    }
}

DEV void ln_row(float* zbase, int lr, int lane, float4 g4, float4 b4) {
    float* row = zbase + lr * 256;
    const float4 v = *(const float4*)(row + lane * 4);
    float s = v.x + v.y + v.z + v.w;
    float ss = fmaf(v.x, v.x, fmaf(v.y, v.y, fmaf(v.z, v.z, v.w * v.w)));
#pragma unroll
    for (int m = 32; m; m >>= 1) { s += __shfl_xor(s, m); ss += __shfl_xor(ss, m); }
    const float mean = s * (1.f / 256.f);
    const float var = ss * (1.f / 256.f) - mean * mean;
    const float rstd = rsqrtf(var + 1e-5f);
    float4 ov;
    ov.x = (v.x - mean) * rstd * g4.x + b4.x;
    ov.y = (v.y - mean) * rstd * g4.y + b4.y;
    ov.z = (v.z - mean) * rstd * g4.z + b4.z;
    ov.w = (v.w - mean) * rstd * g4.w + b4.w;
    *(float4*)(row + lane * 4) = ov;
}

__global__ __launch_bounds__(512) void k_hrm(const float* __restrict__ be,
        const float* __restrict__ L1T, const float* __restrict__ L1b,
        const float* __restrict__ L2T, const float* __restrict__ L2b,
        const float* __restrict__ Lg, const float* __restrict__ Lbt,
        const float* __restrict__ H1T, const float* __restrict__ H1b,
        const float* __restrict__ H2T, const float* __restrict__ H2b,
        const float* __restrict__ Hg, const float* __restrict__ Hbt,
        const float* __restrict__ v1T, const float* __restrict__ v1bp,
        const float* __restrict__ v2T, const float* __restrict__ v2bp,
        float* __restrict__ out) {
    __shared__ __align__(16) float zL[8][256];
    __shared__ __align__(16) float zH[8][256];
    __shared__ __align__(16) float beS[8][256];
    __shared__ __align__(16) float h1[8][256];
    const int t = threadIdx.x;
    const int b0 = blockIdx.x * 8;
    for (int idx = t; idx < 2048; idx += 512) {
        const int r = idx >> 8, c = idx & 255;
        zL[r][c] = 0.f;
        zH[r][c] = 0.f;
        beS[r][c] = be[(size_t)(b0 + r) * 256 + c];
    }
    const int o = t & 255;
    const int rg = (t >> 8) * 4;  // rows rg..rg+3
    const float l1bias = L1b[o], l2bias = L2b[o];
    const float h1bias = H1b[o], h2bias = H2b[o], v1bias = v1bp[o];
    const int lane = t & 63;
    const int lrow = t >> 6;  // 0..7
    const float4 Lg4 = *(const float4*)(Lg + lane * 4);
    const float4 Lb4 = *(const float4*)(Lbt + lane * 4);
    const float4 Hg4 = *(const float4*)(Hg + lane * 4);
    const float4 Hb4 = *(const float4*)(Hbt + lane * 4);
    __syncthreads();
    for (int it = 0; it < 64; ++it) {
        // ---- Lnet: h1 = relu(cat(zL,zH,be) @ L1^T + b) ----
        float acc[4];
#pragma unroll
        for (int i = 0; i < 4; ++i) acc[i] = l1bias;
        dot_seg(acc, &zL[rg][0], L1T, o);
        dot_seg(acc, &zH[rg][0], L1T + 256 * 256, o);
        dot_seg(acc, &beS[rg][0], L1T + 512 * 256, o);
#pragma unroll
        for (int i = 0; i < 4; ++i) h1[rg + i][o] = fmaxf(acc[i], 0.f);
        __syncthreads();
        // ---- zL = LN(relu(h1 @ L2^T + b)) ----
#pragma unroll
        for (int i = 0; i < 4; ++i) acc[i] = l2bias;
        dot_seg(acc, &h1[rg][0], L2T, o);
#pragma unroll
        for (int i = 0; i < 4; ++i) zL[rg + i][o] = fmaxf(acc[i], 0.f);
        __syncthreads();
        ln_row(&zL[0][0], lrow, lane, Lg4, Lb4);
        __syncthreads();
        if (((it + 1) & 7) == 0) {
            // ---- Hnet: zH = LN(relu(relu(cat(zH,zL) @ H1^T + b) @ H2^T + b)) ----
#pragma unroll
            for (int i = 0; i < 4; ++i) acc[i] = h1bias;
            dot_seg(acc, &zH[rg][0], H1T, o);
            dot_seg(acc, &zL[rg][0], H1T + 256 * 256, o);
#pragma unroll
            for (int i = 0; i < 4; ++i) h1[rg + i][o] = fmaxf(acc[i], 0.f);
            __syncthreads();
#pragma unroll
            for (int i = 0; i < 4; ++i) acc[i] = h2bias;
            dot_seg(acc, &h1[rg][0], H2T, o);
#pragma unroll
            for (int i = 0; i < 4; ++i) zH[rg + i][o] = fmaxf(acc[i], 0.f);
            __syncthreads();
            ln_row(&zH[0][0], lrow, lane, Hg4, Hb4);
            __syncthreads();
        }
    }
    // ---- head: out = relu(zH @ v1^T + b) @ v2^T + b ----
    float acc[4];
#pragma unroll
    for (int i = 0; i < 4; ++i) acc[i] = v1bias;
    dot_seg(acc, &zH[rg][0], v1T, o);
#pragma unroll
    for (int i = 0; i < 4; ++i) h1[rg + i][o] = fmaxf(acc[i], 0.f);
    __syncthreads();
    for (int idx = t; idx < 1024; idx += 512) {
        const int r = idx >> 7, oo = idx & 127;
        float s = v2bp[oo];
        for (int kk = 0; kk < 256; kk += 4) {
            const float4 c4 = *(const float4*)(&h1[r][kk]);
            s = fmaf(c4.x, v2T[(kk + 0) * 128 + oo], s);
            s = fmaf(c4.y, v2T[(kk + 1) * 128 + oo], s);
            s = fmaf(c4.z, v2T[(kk + 2) * 128 + oo], s);
            s = fmaf(c4.w, v2T[(kk + 3) * 128 + oo], s);
        }
        out[(size_t)(b0 + r) * 128 + oo] = s;
    }
}

// ================================================================ launch
extern "C" void kernel_launch(void* const* d_in, const int* in_sizes, int n_in,
                              void* d_out, int out_size, void* d_ws, size_t ws_size,
                              hipStream_t stream) {
    const float* bitplanes  = (const float*)d_in[0];
    const float* conv1_w    = (const float*)d_in[1];
    const float* conv1_b    = (const float*)d_in[2];
    const float* conv2_w    = (const float*)d_in[3];
    const float* conv2_b    = (const float*)d_in[4];
    const float* in_proj_w  = (const float*)d_in[5];
    const float* in_proj_b  = (const float*)d_in[6];
    const float* out_proj_w = (const float*)d_in[7];
    const float* out_proj_b = (const float*)d_in[8];
    const float* ln1_g      = (const float*)d_in[9];
    const float* ln1_b      = (const float*)d_in[10];
    const float* ff1_w      = (const float*)d_in[11];
    const float* ff1_b      = (const float*)d_in[12];
    const float* ff2_w      = (const float*)d_in[13];
    const float* ff2_b      = (const float*)d_in[14];
    const float* ln2_g      = (const float*)d_in[15];
    const float* ln2_b      = (const float*)d_in[16];
    const float* be1_w      = (const float*)d_in[17];
    const float* be1_b      = (const float*)d_in[18];
    const float* be2_w      = (const float*)d_in[19];
    const float* be2_b      = (const float*)d_in[20];
    const float* L1_w       = (const float*)d_in[21];
    const float* L1_b       = (const float*)d_in[22];
    const float* L2_w       = (const float*)d_in[23];
    const float* L2_b       = (const float*)d_in[24];
    const float* Lln_g      = (const float*)d_in[25];
    const float* Lln_b      = (const float*)d_in[26];
    const float* H1_w       = (const float*)d_in[27];
    const float* H1_b       = (const float*)d_in[28];
    const float* H2_w       = (const float*)d_in[29];
    const float* H2_b       = (const float*)d_in[30];
    const float* Hln_g      = (const float*)d_in[31];
    const float* Hln_b      = (const float*)d_in[32];
    const float* v1_w       = (const float*)d_in[33];
    const float* v1_b       = (const float*)d_in[34];
    const float* v2_w       = (const float*)d_in[35];
    const float* v2_b       = (const float*)d_in[36];

    // --- runtime chunk sizing: per-chunk floats = CB*65536, persistent tail = 2,392,064 floats ---
    const size_t persist = 2392064ull;
    int CB = 64;
    for (int c = 2048; c >= 64; c >>= 1) {
        size_t needBytes = ((size_t)c * 65536ull + persist) * 4ull;
        if (needBytes <= ws_size) { CB = c; break; }
    }
    const int NCH = 2048 / CB;

    float* ws = (float*)d_ws;
    float* a1buf = ws;                                 // CB*16384
    float* xbuf  = a1buf + (size_t)CB * 16384;         // CB*16384
    float* tbuf  = xbuf + (size_t)CB * 16384;          // CB*32768
    float* wqkvT = tbuf + (size_t)CB * 32768;          // 196,608
    float* w2t   = wqkvT + 196608;                     // 589,824
    float* L1T   = w2t + 589824;                       // 196,608
    float* L2T   = L1T + 196608;                       // 65,536
    float* H1T   = L2T + 65536;                        // 131,072
    float* H2T   = H1T + 131072;                       // 65,536
    float* v1T   = H2T + 65536;                        // 65,536
    float* v2T   = v1T + 65536;                        // 32,768
    float* beB   = v2T + 32768;                        // 524,288
    float* bemid = beB + 524288;                       // 524,288

    // weight transposes (once)
    k_tpose<<<256, 256, 0, stream>>>(in_proj_w, wqkvT, 768, 256);
    k_tpose<<<512, 256, 0, stream>>>(conv2_w, w2t, 256, 2304);
    k_tpose<<<256, 256, 0, stream>>>(L1_w, L1T, 256, 768);
    k_tpose<<<128, 256, 0, stream>>>(L2_w, L2T, 256, 256);
    k_tpose<<<128, 256, 0, stream>>>(H1_w, H1T, 256, 512);
    k_tpose<<<128, 256, 0, stream>>>(H2_w, H2T, 256, 256);
    k_tpose<<<128, 256, 0, stream>>>(v1_w, v1T, 256, 256);
    k_tpose<<<64, 256, 0, stream>>>(v2_w, v2T, 128, 256);

    for (int ch = 0; ch < NCH; ++ch) {
        const float* bp_c = bitplanes + (size_t)ch * CB * 20 * 64;
        // conv encoder
        k_conv1<<<CB, 256, 0, stream>>>(bp_c, conv1_w, conv1_b, a1buf);
        k_conv2<<<CB, 256, 0, stream>>>(a1buf, w2t, conv2_b, xbuf);
        // transformer layer
        k_attn<<<dim3(CB, 4), 512, 0, stream>>>(xbuf, wqkvT, in_proj_b, a1buf);
        k_gemm<<<dim3(CB, 4, 1), 256, 0, stream>>>(a1buf, out_proj_w, out_proj_b, tbuf,
                                                   CB * 64, 256, 256, 256, 0);
        k_ln_add<<<CB * 16, 256, 0, stream>>>(xbuf, tbuf, ln1_g, ln1_b);
        k_gemm<<<dim3(CB, 8, 1), 256, 0, stream>>>(xbuf, ff1_w, ff1_b, tbuf,
                                                   CB * 64, 512, 256, 256, 1);
        k_gemm<<<dim3(CB, 4, 1), 256, 0, stream>>>(tbuf, ff2_w, ff2_b, a1buf,
                                                   CB * 64, 256, 512, 512, 0);
        k_ln_add<<<CB * 16, 256, 0, stream>>>(xbuf, a1buf, ln2_g, ln2_b);
        // board embedding: be = relu(relu(xf@be1^T+b)@be2^T+b)
        k_gemm<<<dim3(CB / 64, 4, 8), 256, 0, stream>>>(xbuf, be1_w, nullptr, tbuf,
                                                        CB, 256, 16384, 2048, 0);
        k_be1_reduce<<<CB, 256, 0, stream>>>(tbuf, be1_b, bemid + (size_t)ch * CB * 256, CB * 256);
        k_gemm<<<dim3(CB / 64, 4, 1), 256, 0, stream>>>(bemid + (size_t)ch * CB * 256, be2_w, be2_b,
                                                        beB + (size_t)ch * CB * 256, CB, 256, 256, 256, 1);
    }

    // HRM recurrence + head (persistent, 8 rows/block)
    k_hrm<<<256, 512, 0, stream>>>(beB, L1T, L1_b, L2T, L2_b, Lln_g, Lln_b,
                                   H1T, H1_b, H2T, H2_b, Hln_g, Hln_b,
                                   v1T, v1_b, v2T, v2_b, (float*)d_out);
}